// Round 5
// baseline (200.841 us; speedup 1.0000x reference)
//
#include <hip/hip_runtime.h>

// Problem constants (B,V,T,H,W) = (32, 8, 2, 192, 288)
#define D        16        // V*T
#define NPAIR    136       // D*(D+1)/2 upper-triangle Gram entries
#define NVALS    152       // NPAIR + D row sums
#define HW       55296     // H*W
#define BSTRIDE  884736    // V*T*H*W (batch stride in floats)
#define NTOT     1769472   // B*H*W = N
#define TCOLS    256       // columns per LDS tile (16 KB per buffer)
#define TPB      4         // tiles per block
#define CPB      1024      // columns per block (HW % 1024 == 0 -> no batch crossing)
#define BPP      54        // blocks per batch-plane (HW / CPB)
#define G        1728      // grid = NTOT / CPB
#define GJ       27        // G / 64 (finalize loads per lane)

__device__ __forceinline__ float wave_reduce(float x) {
    x += __shfl_down(x, 32);
    x += __shfl_down(x, 16);
    x += __shfl_down(x, 8);
    x += __shfl_down(x, 4);
    x += __shfl_down(x, 2);
    x += __shfl_down(x, 1);
    return x;
}

__host__ __device__ constexpr int tri_idx(int d, int e) {
    // d <= e required
    return d * D - (d * (d - 1)) / 2 + (e - d);
}

// 8 waves/block. Wave W owns rows {W, 15-W}: pairs (W,e) e>=W  (16-W of them)
// plus (15-W,e) e>=15-W  (W+1 of them) = exactly 17 pairs + 2 row sums.
// Per-thread live state ~60 VGPRs -> 4 waves/SIMD band (round-4 was 136 VGPR
// -> 2 waves/SIMD -> latency-bound at 11% occupancy).
// LDS residual tile is double-buffered; tile t+1's global loads are issued
// before tile t's compute (async-stage split) so HBM latency hides under
// compute. One barrier per tile: write -> barrier -> compute. (The write of
// tile t+2 into this buffer sits behind barrier(t+1), which all waves only
// pass after finishing compute(t).)
template<int W>
__device__ __forceinline__ void gram_wave(const float* __restrict__ bt,
                                          const float* __restrict__ bp,
                                          float (*tile)[D][TCOLS],
                                          float* __restrict__ part,
                                          int blk, int tid) {
    constexpr int R = W;          // first owned row (reads rows R..15)
    constexpr int Q = 15 - W;     // second owned row

    float accA[D - R];
    float accB[D - Q];
    float sA = 0.0f, sB = 0.0f;
#pragma unroll
    for (int j = 0; j < D - R; ++j) accA[j] = 0.0f;
#pragma unroll
    for (int j = 0; j < D - Q; ++j) accB[j] = 0.0f;

    const int lane = tid & 63;
    const int row  = tid >> 6;          // 0..7 (this thread stages rows row, row+8)
    const int cq   = (tid & 63) * 4;    // float4 column offset within tile

    const float* t0 = bt + row * HW + cq;
    const float* t8 = bt + (row + 8) * HW + cq;
    const float* p0 = bp + row * HW + cq;
    const float* p8 = bp + (row + 8) * HW + cq;

    float4 r0, r1;   // staged residual payload for the upcoming tile
    {
        const float4 a = *reinterpret_cast<const float4*>(t0);
        const float4 b = *reinterpret_cast<const float4*>(p0);
        const float4 c = *reinterpret_cast<const float4*>(t8);
        const float4 d = *reinterpret_cast<const float4*>(p8);
        r0 = make_float4(a.x - b.x, a.y - b.y, a.z - b.z, a.w - b.w);
        r1 = make_float4(c.x - d.x, c.y - d.y, c.z - d.z, c.w - d.w);
    }

#pragma unroll
    for (int t = 0; t < TPB; ++t) {
        float (*buf)[TCOLS] = tile[t & 1];
        *reinterpret_cast<float4*>(&buf[row][cq])     = r0;
        *reinterpret_cast<float4*>(&buf[row + 8][cq]) = r1;
        __syncthreads();
        if (t + 1 < TPB) {   // issue next tile's loads; consumed at next ds_write
            const int off = (t + 1) * TCOLS;
            const float4 a = *reinterpret_cast<const float4*>(t0 + off);
            const float4 b = *reinterpret_cast<const float4*>(p0 + off);
            const float4 c = *reinterpret_cast<const float4*>(t8 + off);
            const float4 d = *reinterpret_cast<const float4*>(p8 + off);
            r0 = make_float4(a.x - b.x, a.y - b.y, a.z - b.z, a.w - b.w);
            r1 = make_float4(c.x - d.x, c.y - d.y, c.z - d.z, c.w - d.w);
        }
        // Compute: lane handles cols j*64+lane; consecutive lanes hit
        // consecutive LDS words -> 2 lanes/bank (free on CDNA4).
#pragma unroll
        for (int j = 0; j < TCOLS / 64; ++j) {
            const int col = j * 64 + lane;
            float rv[D];
#pragma unroll
            for (int d = R; d < D; ++d) rv[d] = buf[d][col];
#pragma unroll
            for (int e = R; e < D; ++e) accA[e - R] += rv[R] * rv[e];
#pragma unroll
            for (int e = Q; e < D; ++e) accB[e - Q] += rv[Q] * rv[e];
            sA += rv[R];
            sB += rv[Q];
        }
    }

    // Epilogue: per-wave shuffle reduce; pair sets are disjoint across waves.
#pragma unroll
    for (int e = R; e < D; ++e) {
        const float v = wave_reduce(accA[e - R]);
        if (lane == 0) part[tri_idx(R, e) * G + blk] = v;
    }
#pragma unroll
    for (int e = Q; e < D; ++e) {
        const float v = wave_reduce(accB[e - Q]);
        if (lane == 0) part[tri_idx(Q, e) * G + blk] = v;
    }
    {
        float v;
        v = wave_reduce(sA); if (lane == 0) part[(NPAIR + R) * G + blk] = v;
        v = wave_reduce(sB); if (lane == 0) part[(NPAIR + Q) * G + blk] = v;
    }
}

__global__ __launch_bounds__(512, 4)
void gram_partial(const float* __restrict__ yt, const float* __restrict__ yp,
                  float* __restrict__ part) {
    __shared__ float tile[2][D][TCOLS];   // 32 KB (double-buffered)
    const int tid = threadIdx.x;
    const int b   = blockIdx.x / BPP;
    const int hw0 = (blockIdx.x - b * BPP) * CPB;
    const float* bt = yt + (size_t)b * BSTRIDE + hw0;
    const float* bp = yp + (size_t)b * BSTRIDE + hw0;
    switch (tid >> 6) {
        case 0:  gram_wave<0>(bt, bp, tile, part, blockIdx.x, tid); break;
        case 1:  gram_wave<1>(bt, bp, tile, part, blockIdx.x, tid); break;
        case 2:  gram_wave<2>(bt, bp, tile, part, blockIdx.x, tid); break;
        case 3:  gram_wave<3>(bt, bp, tile, part, blockIdx.x, tid); break;
        case 4:  gram_wave<4>(bt, bp, tile, part, blockIdx.x, tid); break;
        case 5:  gram_wave<5>(bt, bp, tile, part, blockIdx.x, tid); break;
        case 6:  gram_wave<6>(bt, bp, tile, part, blockIdx.x, tid); break;
        default: gram_wave<7>(bt, bp, tile, part, blockIdx.x, tid); break;
    }
}

// Pass 2 (single block, 256 threads): reduce partials, build cov, invert
// 16x16 via cooperative Gauss-Jordan, emit (1/N) * sum(P .* S).
__global__ void finalize_kernel(const float* __restrict__ part,
                                float* __restrict__ out) {
    __shared__ float Stri[NPAIR];
    __shared__ float Ssum[D];
    __shared__ float A[D][2 * D + 1];   // [cov | I], padded row

    const int tid  = threadIdx.x;
    const int lane = tid & 63;
    const int wv   = tid >> 6;

    // 1) Reduce G block-partials per value: one wave per value row.
    for (int vi = wv; vi < NVALS; vi += 4) {
        float s = 0.0f;
#pragma unroll
        for (int j = 0; j < GJ; ++j)
            s += part[vi * G + j * 64 + lane];
        s = wave_reduce(s);
        if (lane == 0) {
            if (vi < NPAIR) Stri[vi]         = s;
            else            Ssum[vi - NPAIR] = s;
        }
    }
    __syncthreads();

    // 2) Augmented matrix [cov | I]
    {
        const int d = tid >> 4, e = tid & 15;
        const int lo = d < e ? d : e, hi = d < e ? e : d;
        const float invN = 1.0f / (float)NTOT;
        const float cov = (Stri[tri_idx(lo, hi)] -
                           Ssum[d] * Ssum[e] * invN) /
                          (float)(NTOT - 1);
        A[d][e]     = cov;
        A[d][D + e] = (d == e) ? 1.0f : 0.0f;
    }
    __syncthreads();

    // 3) Gauss-Jordan (no pivoting; cov ~ 0.01*I, well-conditioned).
    const int r0 = tid >> 5;   // 0..7
    const int c0 = tid & 31;   // 0..31
    const int r1 = r0 + 8;
    for (int k = 0; k < D; ++k) {
        const float pivinv = 1.0f / A[k][k];
        __syncthreads();
        if (tid < 32) A[k][tid] *= pivinv;
        __syncthreads();
        const float f0 = A[r0][k];
        const float f1 = A[r1][k];
        __syncthreads();
        const float akc = A[k][c0];
        if (r0 != k) A[r0][c0] -= f0 * akc;
        if (r1 != k) A[r1][c0] -= f1 * akc;
        __syncthreads();
    }

    // 4) result = (1/N) * sum_{d,e} P[d][e] * S[d][e]
    float term;
    {
        const int d = tid >> 4, e = tid & 15;
        const int lo = d < e ? d : e, hi = d < e ? e : d;
        float p = A[d][D + e];
        const float scale = 1.0f;  // OFF_DIAGONAL_SCALE
        if (d != e) p *= scale;
        term = p * Stri[tri_idx(lo, hi)];
    }
    term = wave_reduce(term);

    __shared__ float wsum[4];
    if (lane == 0) wsum[wv] = term;
    __syncthreads();
    if (tid == 0) {
        const float tot = (wsum[0] + wsum[1]) + (wsum[2] + wsum[3]);
        out[0] = tot / (float)NTOT;
    }
}

extern "C" void kernel_launch(void* const* d_in, const int* in_sizes, int n_in,
                              void* d_out, int out_size, void* d_ws, size_t ws_size,
                              hipStream_t stream) {
    const float* y_true = (const float*)d_in[0];
    const float* y_pred = (const float*)d_in[1];
    float* out  = (float*)d_out;
    float* part = (float*)d_ws;   // needs NVALS * G * 4 = 1,050,624 bytes

    hipLaunchKernelGGL(gram_partial, dim3(G), dim3(512), 0, stream,
                       y_true, y_pred, part);
    hipLaunchKernelGGL(finalize_kernel, dim3(1), dim3(256), 0, stream,
                       part, out);
}

// Round 6
// 71.516 us; speedup vs baseline: 2.8083x; 2.8083x over previous
//
#include <hip/hip_runtime.h>

// Problem constants (B,V,T,H,W) = (32, 8, 2, 192, 288)
#define D        16        // V*T
#define NPAIR    136       // D*(D+1)/2 upper-triangle Gram entries
#define NVALS    152       // NPAIR + D row sums
#define HW       55296     // H*W
#define BSTRIDE  884736    // V*T*H*W (batch stride in floats)
#define NTOT     1769472   // B*H*W = N
#define CPB      1024      // columns per block (HW % 1024 == 0 -> no batch crossing)
#define BPP      54        // blocks per batch-plane (HW / CPB)
#define G        1728      // grid = NTOT / CPB
#define GJ       27        // G / 64 (finalize loads per lane)
#define CHUNKS   8         // 32-column MFMA chunks per wave (4 waves x 256 cols = CPB)

typedef __attribute__((ext_vector_type(8))) short short8;
typedef __attribute__((ext_vector_type(4))) float f32x4;

__device__ __forceinline__ float wave_reduce(float x) {
    x += __shfl_down(x, 32);
    x += __shfl_down(x, 16);
    x += __shfl_down(x, 8);
    x += __shfl_down(x, 4);
    x += __shfl_down(x, 2);
    x += __shfl_down(x, 1);
    return x;
}

__host__ __device__ constexpr int tri_idx(int d, int e) {
    // d <= e required
    return d * D - (d * (d - 1)) / 2 + (e - d);
}

__device__ __forceinline__ short f2bf(float x) {
    // fp32 -> bf16 round-to-nearest-even on the bit pattern
    union { float f; unsigned u; } v; v.f = x;
    const unsigned r = (v.u + 0x7fffu + ((v.u >> 16) & 1u)) >> 16;
    return (short)r;
}

// S = R * R^T via mfma_f32_16x16x32_bf16. For this shape the A-fragment
// (lane l holds A[l&15][(l>>4)*8+j]) and the B-fragment of R^T
// (lane l holds B[(l>>4)*8+j][l&15] = R[l&15][(l>>4)*8+j]) are the SAME
// registers -> pass one fragment twice. No LDS tile, no 34-wide scalar
// accumulator arrays (rounds 1-5 all died on register pressure/spills:
// scalar structure needs ~136 VGPR; this needs ~50).
// Row sums (for the mean term) are accumulated from the fp32 residuals.
__global__ __launch_bounds__(256)
void gram_mfma(const float* __restrict__ yt, const float* __restrict__ yp,
               float* __restrict__ part) {
    const int tid  = threadIdx.x;
    const int lane = tid & 63;
    const int wid  = tid >> 6;
    const int b    = blockIdx.x / BPP;
    const int hw0  = (blockIdx.x - b * BPP) * CPB + wid * (CHUNKS * 32);
    const int row  = lane & 15;          // MFMA row this lane feeds
    const int koff = (lane >> 4) * 8;    // k-slice within the 32-col chunk

    const float* t0 = yt + (size_t)b * BSTRIDE + row * HW + hw0 + koff;
    const float* p0 = yp + (size_t)b * BSTRIDE + row * HW + hw0 + koff;

    f32x4 acc = {0.0f, 0.0f, 0.0f, 0.0f};
    float rs = 0.0f;

#pragma unroll 2
    for (int c = 0; c < CHUNKS; ++c) {
        const int off = c * 32;
        const float4 a0 = *reinterpret_cast<const float4*>(t0 + off);
        const float4 a1 = *reinterpret_cast<const float4*>(t0 + off + 4);
        const float4 q0 = *reinterpret_cast<const float4*>(p0 + off);
        const float4 q1 = *reinterpret_cast<const float4*>(p0 + off + 4);
        const float r0 = a0.x - q0.x, r1 = a0.y - q0.y;
        const float r2 = a0.z - q0.z, r3 = a0.w - q0.w;
        const float r4 = a1.x - q1.x, r5 = a1.y - q1.y;
        const float r6 = a1.z - q1.z, r7 = a1.w - q1.w;
        rs += ((r0 + r1) + (r2 + r3)) + ((r4 + r5) + (r6 + r7));
        short8 f;
        f[0] = f2bf(r0); f[1] = f2bf(r1); f[2] = f2bf(r2); f[3] = f2bf(r3);
        f[4] = f2bf(r4); f[5] = f2bf(r5); f[6] = f2bf(r6); f[7] = f2bf(r7);
        acc = __builtin_amdgcn_mfma_f32_16x16x32_bf16(f, f, acc, 0, 0, 0);
    }

    // Row sum: combine the 4 k-slice lanes of each row (bits 4,5 of lane).
    rs += __shfl_xor(rs, 16);
    rs += __shfl_xor(rs, 32);

    // Block reduction: 4 waves' C tiles + row sums via LDS (epilogue only).
    __shared__ float cpart[4][D][D];
    __shared__ float spart[4][D];
    // C/D layout: col = lane&15, row = (lane>>4)*4 + i   [m89-verified]
#pragma unroll
    for (int i = 0; i < 4; ++i)
        cpart[wid][(lane >> 4) * 4 + i][row] = acc[i];
    if (lane < D) spart[wid][lane] = rs;
    __syncthreads();

    const int d = tid >> 4, e = tid & 15;
    if (d <= e) {
        const float s = (cpart[0][d][e] + cpart[1][d][e]) +
                        (cpart[2][d][e] + cpart[3][d][e]);
        part[tri_idx(d, e) * G + blockIdx.x] = s;
    }
    if (tid < D) {
        const float s = (spart[0][tid] + spart[1][tid]) +
                        (spart[2][tid] + spart[3][tid]);
        part[(NPAIR + tid) * G + blockIdx.x] = s;
    }
}

// Pass 2 (single block, 256 threads): reduce partials, build cov, invert
// 16x16 via cooperative Gauss-Jordan, emit (1/N) * sum(P .* S).
__global__ void finalize_kernel(const float* __restrict__ part,
                                float* __restrict__ out) {
    __shared__ float Stri[NPAIR];
    __shared__ float Ssum[D];
    __shared__ float A[D][2 * D + 1];   // [cov | I], padded row

    const int tid  = threadIdx.x;
    const int lane = tid & 63;
    const int wv   = tid >> 6;

    // 1) Reduce G block-partials per value: one wave per value row.
    for (int vi = wv; vi < NVALS; vi += 4) {
        float s = 0.0f;
#pragma unroll
        for (int j = 0; j < GJ; ++j)
            s += part[vi * G + j * 64 + lane];
        s = wave_reduce(s);
        if (lane == 0) {
            if (vi < NPAIR) Stri[vi]         = s;
            else            Ssum[vi - NPAIR] = s;
        }
    }
    __syncthreads();

    // 2) Augmented matrix [cov | I]
    {
        const int d = tid >> 4, e = tid & 15;
        const int lo = d < e ? d : e, hi = d < e ? e : d;
        const float invN = 1.0f / (float)NTOT;
        const float cov = (Stri[tri_idx(lo, hi)] -
                           Ssum[d] * Ssum[e] * invN) /
                          (float)(NTOT - 1);
        A[d][e]     = cov;
        A[d][D + e] = (d == e) ? 1.0f : 0.0f;
    }
    __syncthreads();

    // 3) Gauss-Jordan (no pivoting; cov ~ 0.01*I, well-conditioned).
    const int r0 = tid >> 5;   // 0..7
    const int c0 = tid & 31;   // 0..31
    const int r1 = r0 + 8;
    for (int k = 0; k < D; ++k) {
        const float pivinv = 1.0f / A[k][k];
        __syncthreads();
        if (tid < 32) A[k][tid] *= pivinv;
        __syncthreads();
        const float f0 = A[r0][k];
        const float f1 = A[r1][k];
        __syncthreads();
        const float akc = A[k][c0];
        if (r0 != k) A[r0][c0] -= f0 * akc;
        if (r1 != k) A[r1][c0] -= f1 * akc;
        __syncthreads();
    }

    // 4) result = (1/N) * sum_{d,e} P[d][e] * S[d][e]
    float term;
    {
        const int d = tid >> 4, e = tid & 15;
        const int lo = d < e ? d : e, hi = d < e ? e : d;
        float p = A[d][D + e];
        const float scale = 1.0f;  // OFF_DIAGONAL_SCALE
        if (d != e) p *= scale;
        term = p * Stri[tri_idx(lo, hi)];
    }
    term = wave_reduce(term);

    __shared__ float wsum[4];
    if (lane == 0) wsum[wv] = term;
    __syncthreads();
    if (tid == 0) {
        const float tot = (wsum[0] + wsum[1]) + (wsum[2] + wsum[3]);
        out[0] = tot / (float)NTOT;
    }
}

extern "C" void kernel_launch(void* const* d_in, const int* in_sizes, int n_in,
                              void* d_out, int out_size, void* d_ws, size_t ws_size,
                              hipStream_t stream) {
    const float* y_true = (const float*)d_in[0];
    const float* y_pred = (const float*)d_in[1];
    float* out  = (float*)d_out;
    float* part = (float*)d_ws;   // needs NVALS * G * 4 = 1,050,624 bytes

    hipLaunchKernelGGL(gram_mfma, dim3(G), dim3(256), 0, stream,
                       y_true, y_pred, part);
    hipLaunchKernelGGL(finalize_kernel, dim3(1), dim3(256), 0, stream,
                       part, out);
}

// Round 7
// 69.593 us; speedup vs baseline: 2.8859x; 1.0276x over previous
//
#include <hip/hip_runtime.h>

// Problem constants (B,V,T,H,W) = (32, 8, 2, 192, 288)
#define D        16        // V*T
#define NPAIR    136       // D*(D+1)/2 upper-triangle Gram entries
#define NVALS    152       // NPAIR + D row sums
#define HW       55296     // H*W
#define BSTRIDE  884736    // V*T*H*W (batch stride in floats)
#define NTOT     1769472   // B*H*W = N
#define CPB      1024      // columns per block (HW % 1024 == 0)
#define BPP      54        // blocks per batch-plane (HW / CPB)
#define G        1728      // grid = NTOT / CPB
#define GJ       27        // G / 64 (finalize loads per lane)
#define TCOLS    512       // columns per LDS tile
#define TPB      2         // tiles per block (TPB * TCOLS == CPB)
#define TSTRIDE  516       // LDS row stride in words: == 4 (mod 32) -> fragment
                           // b128 reads land 8/bank uniformly (conflict floor)

typedef __attribute__((ext_vector_type(8))) short short8;
typedef __attribute__((ext_vector_type(4))) float f32x4;

__device__ __forceinline__ float wave_reduce(float x) {
    x += __shfl_down(x, 32);
    x += __shfl_down(x, 16);
    x += __shfl_down(x, 8);
    x += __shfl_down(x, 4);
    x += __shfl_down(x, 2);
    x += __shfl_down(x, 1);
    return x;
}

__host__ __device__ constexpr int tri_idx(int d, int e) {
    // d <= e required
    return d * D - (d * (d - 1)) / 2 + (e - d);
}

__device__ __forceinline__ short f2bf(float x) {
    // fp32 -> bf16 round-to-nearest-even on the bit pattern
    union { float f; unsigned u; } v; v.f = x;
    const unsigned r = (v.u + 0x7fffu + ((v.u >> 16) & 1u)) >> 16;
    return (short)r;
}

// Round-6 post-mortem: direct per-lane global fragment loads made every wave
// load a 16-row scatter at stride 216 KB = 27 x 8 KB -> all rows in the SAME
// L1 set -> miss-pipe throttled at 1.3 TB/s. Fix: stage a [16][512] fp32
// residual tile via fully-coalesced float4 loads (2-KB contiguous runs),
// then feed mfma_f32_16x16x32_bf16 fragments from LDS. A- and B-fragments of
// R and R^T coincide -> one fragment passed twice gives S = R R^T.
__global__ __launch_bounds__(256, 4)
void gram_mfma(const float* __restrict__ yt, const float* __restrict__ yp,
               float* __restrict__ part) {
    __shared__ __align__(16) float tile[D][TSTRIDE];   // 33,024 B

    const int tid  = threadIdx.x;
    const int lane = tid & 63;
    const int wid  = tid >> 6;
    const int b    = blockIdx.x / BPP;
    const int hw0  = (blockIdx.x - b * BPP) * CPB;
    const float* bt = yt + (size_t)b * BSTRIDE + hw0;
    const float* bp = yp + (size_t)b * BSTRIDE + hw0;

    const int row = lane & 15;         // MFMA row this lane feeds
    const int kg  = lane >> 4;         // k-slice group (0..3)

    f32x4 acc = {0.0f, 0.0f, 0.0f, 0.0f};
    float rs = 0.0f;

    for (int t = 0; t < TPB; ++t) {
        // ---- stage: residual tile, coalesced (per instr: 2 rows x 2 KB) ----
#pragma unroll
        for (int s = 0; s < 8; ++s) {
            const int idx = s * 256 + tid;      // 0..2047
            const int r   = idx >> 7;           // 128 float4 per row
            const int c4  = idx & 127;
            const float* ga = bt + r * HW + t * TCOLS + c4 * 4;
            const float* gq = bp + r * HW + t * TCOLS + c4 * 4;
            const float4 a = *reinterpret_cast<const float4*>(ga);
            const float4 q = *reinterpret_cast<const float4*>(gq);
            const float4 rr = make_float4(a.x - q.x, a.y - q.y,
                                          a.z - q.z, a.w - q.w);
            *reinterpret_cast<float4*>(&tile[r][c4 * 4]) = rr;
        }
        __syncthreads();
        // ---- compute: wave covers 128 cols = 4 MFMA chunks ----
#pragma unroll
        for (int c = 0; c < 4; ++c) {
            const float* src = &tile[row][wid * 128 + c * 32 + kg * 8];
            const float v0 = src[0], v1 = src[1], v2 = src[2], v3 = src[3];
            const float v4 = src[4], v5 = src[5], v6 = src[6], v7 = src[7];
            rs += ((v0 + v1) + (v2 + v3)) + ((v4 + v5) + (v6 + v7));
            short8 f;
            f[0] = f2bf(v0); f[1] = f2bf(v1); f[2] = f2bf(v2); f[3] = f2bf(v3);
            f[4] = f2bf(v4); f[5] = f2bf(v5); f[6] = f2bf(v6); f[7] = f2bf(v7);
            acc = __builtin_amdgcn_mfma_f32_16x16x32_bf16(f, f, acc, 0, 0, 0);
        }
        __syncthreads();   // tile fully consumed before next stage overwrites
    }

    // Row sum: combine the 4 k-slice lanes of each row (bits 4,5 of lane).
    rs += __shfl_xor(rs, 16);
    rs += __shfl_xor(rs, 32);

    // Block reduction: 4 waves' C tiles + row sums via LDS (epilogue only).
    __shared__ float cpart[4][D][D];
    __shared__ float spart[4][D];
    // C/D layout: col = lane&15, row = (lane>>4)*4 + i   [m89-verified]
#pragma unroll
    for (int i = 0; i < 4; ++i)
        cpart[wid][kg * 4 + i][row] = acc[i];
    if (lane < D) spart[wid][lane] = rs;
    __syncthreads();

    const int d = tid >> 4, e = tid & 15;
    if (d <= e) {
        const float s = (cpart[0][d][e] + cpart[1][d][e]) +
                        (cpart[2][d][e] + cpart[3][d][e]);
        part[tri_idx(d, e) * G + blockIdx.x] = s;
    }
    if (tid < D) {
        const float s = (spart[0][tid] + spart[1][tid]) +
                        (spart[2][tid] + spart[3][tid]);
        part[(NPAIR + tid) * G + blockIdx.x] = s;
    }
}

// Pass 2 (single block, 256 threads): reduce partials, build cov, invert
// 16x16 via cooperative Gauss-Jordan, emit (1/N) * sum(P .* S).
__global__ void finalize_kernel(const float* __restrict__ part,
                                float* __restrict__ out) {
    __shared__ float Stri[NPAIR];
    __shared__ float Ssum[D];
    __shared__ float A[D][2 * D + 1];   // [cov | I], padded row

    const int tid  = threadIdx.x;
    const int lane = tid & 63;
    const int wv   = tid >> 6;

    // 1) Reduce G block-partials per value: one wave per value row.
    for (int vi = wv; vi < NVALS; vi += 4) {
        float s = 0.0f;
#pragma unroll
        for (int j = 0; j < GJ; ++j)
            s += part[vi * G + j * 64 + lane];
        s = wave_reduce(s);
        if (lane == 0) {
            if (vi < NPAIR) Stri[vi]         = s;
            else            Ssum[vi - NPAIR] = s;
        }
    }
    __syncthreads();

    // 2) Augmented matrix [cov | I]
    {
        const int d = tid >> 4, e = tid & 15;
        const int lo = d < e ? d : e, hi = d < e ? e : d;
        const float invN = 1.0f / (float)NTOT;
        const float cov = (Stri[tri_idx(lo, hi)] -
                           Ssum[d] * Ssum[e] * invN) /
                          (float)(NTOT - 1);
        A[d][e]     = cov;
        A[d][D + e] = (d == e) ? 1.0f : 0.0f;
    }
    __syncthreads();

    // 3) Gauss-Jordan (no pivoting; cov ~ 0.01*I, well-conditioned).
    const int r0 = tid >> 5;   // 0..7
    const int c0 = tid & 31;   // 0..31
    const int r1 = r0 + 8;
    for (int k = 0; k < D; ++k) {
        const float pivinv = 1.0f / A[k][k];
        __syncthreads();
        if (tid < 32) A[k][tid] *= pivinv;
        __syncthreads();
        const float f0 = A[r0][k];
        const float f1 = A[r1][k];
        __syncthreads();
        const float akc = A[k][c0];
        if (r0 != k) A[r0][c0] -= f0 * akc;
        if (r1 != k) A[r1][c0] -= f1 * akc;
        __syncthreads();
    }

    // 4) result = (1/N) * sum_{d,e} P[d][e] * S[d][e]
    float term;
    {
        const int d = tid >> 4, e = tid & 15;
        const int lo = d < e ? d : e, hi = d < e ? e : d;
        float p = A[d][D + e];
        const float scale = 1.0f;  // OFF_DIAGONAL_SCALE
        if (d != e) p *= scale;
        term = p * Stri[tri_idx(lo, hi)];
    }
    term = wave_reduce(term);

    __shared__ float wsum[4];
    if (lane == 0) wsum[wv] = term;
    __syncthreads();
    if (tid == 0) {
        const float tot = (wsum[0] + wsum[1]) + (wsum[2] + wsum[3]);
        out[0] = tot / (float)NTOT;
    }
}

extern "C" void kernel_launch(void* const* d_in, const int* in_sizes, int n_in,
                              void* d_out, int out_size, void* d_ws, size_t ws_size,
                              hipStream_t stream) {
    const float* y_true = (const float*)d_in[0];
    const float* y_pred = (const float*)d_in[1];
    float* out  = (float*)d_out;
    float* part = (float*)d_ws;   // needs NVALS * G * 4 = 1,050,624 bytes

    hipLaunchKernelGGL(gram_mfma, dim3(G), dim3(256), 0, stream,
                       y_true, y_pred, part);
    hipLaunchKernelGGL(finalize_kernel, dim3(1), dim3(256), 0, stream,
                       part, out);
}

// Round 8
// 69.273 us; speedup vs baseline: 2.8993x; 1.0046x over previous
//
#include <hip/hip_runtime.h>

// Problem constants (B,V,T,H,W) = (32, 8, 2, 192, 288)
#define D        16        // V*T
#define NPAIR    136       // D*(D+1)/2 upper-triangle Gram entries
#define NVALS    152       // NPAIR + D row sums
#define HW       55296     // H*W
#define BSTRIDE  884736    // V*T*H*W (batch stride in floats)
#define NTOT     1769472   // B*H*W = N
#define CPB      1024      // columns per block (HW % 1024 == 0)
#define BPP      54        // blocks per batch-plane (HW / CPB)
#define G        1728      // grid = NTOT / CPB
#define GJ       27        // G / 64 (finalize loads per lane)
#define TCOLS    512       // columns per LDS tile
#define TPB      2         // tiles per block (TPB * TCOLS == CPB)
#define TSTRIDE  516       // LDS row stride in words (== 4 mod 32: fragment
                           // b128 reads spread 8 lanes/bank-quad uniformly)

typedef __attribute__((ext_vector_type(8))) short short8;
typedef __attribute__((ext_vector_type(4))) float f32x4;

__device__ __forceinline__ float wave_reduce(float x) {
    x += __shfl_down(x, 32);
    x += __shfl_down(x, 16);
    x += __shfl_down(x, 8);
    x += __shfl_down(x, 4);
    x += __shfl_down(x, 2);
    x += __shfl_down(x, 1);
    return x;
}

__host__ __device__ constexpr int tri_idx(int d, int e) {
    // d <= e required
    return d * D - (d * (d - 1)) / 2 + (e - d);
}

__device__ __forceinline__ short f2bf(float x) {
    // fp32 -> bf16 round-to-nearest-even on the bit pattern
    union { float f; unsigned u; } v; v.f = x;
    const unsigned r = (v.u + 0x7fffu + ((v.u >> 16) & 1u)) >> 16;
    return (short)r;
}

// Rounds 6 & 7 both plateaued at ~2.7 TB/s delivered regardless of staging
// style. Common invariant: the 16-row gather at stride 216 KB = 27 x 8 KB,
// i.e. ALL 32 miss streams (16 rows x 2 inputs) are congruent mod the L1
// set span (8 KB) -> per-set outstanding-miss serialization in the TCP.
// Fix: rotate each row's column traversal by r*512 B (4 L1 sets). Every row
// still covers the same column set per tile (Gram exact; LDS slot matches
// the global column), but concurrent streams now sit at 16 distinct set
// offsets instead of 1.
__global__ __launch_bounds__(256, 4)
void gram_mfma(const float* __restrict__ yt, const float* __restrict__ yp,
               float* __restrict__ part) {
    __shared__ __align__(16) float tile[D][TSTRIDE];   // 33,024 B

    const int tid  = threadIdx.x;
    const int lane = tid & 63;
    const int wid  = tid >> 6;
    const int b    = blockIdx.x / BPP;
    const int hw0  = (blockIdx.x - b * BPP) * CPB;
    const float* bt = yt + (size_t)b * BSTRIDE + hw0;
    const float* bp = yp + (size_t)b * BSTRIDE + hw0;

    const int row = lane & 15;         // MFMA row this lane feeds
    const int kg  = lane >> 4;         // k-slice group (0..3)

    f32x4 acc = {0.0f, 0.0f, 0.0f, 0.0f};
    float rs = 0.0f;

    for (int t = 0; t < TPB; ++t) {
        // ---- stage: residual tile, coalesced, per-row set-rotated ----
#pragma unroll
        for (int s = 0; s < 8; ++s) {
            const int idx = s * 256 + tid;      // 0..2047
            const int r   = idx >> 7;           // 128 float4 per row
            const int c4  = idx & 127;
            const int c4r = (c4 + r * 32) & 127;   // +r*512B: L1-set spread
            const float* ga = bt + r * HW + t * TCOLS + c4r * 4;
            const float* gq = bp + r * HW + t * TCOLS + c4r * 4;
            const float4 a = *reinterpret_cast<const float4*>(ga);
            const float4 q = *reinterpret_cast<const float4*>(gq);
            const float4 rr = make_float4(a.x - q.x, a.y - q.y,
                                          a.z - q.z, a.w - q.w);
            *reinterpret_cast<float4*>(&tile[r][c4r * 4]) = rr;
        }
        __syncthreads();
        // ---- compute: wave covers 128 cols = 4 MFMA chunks ----
#pragma unroll
        for (int c = 0; c < 4; ++c) {
            const float* src = &tile[row][wid * 128 + c * 32 + kg * 8];
            const float v0 = src[0], v1 = src[1], v2 = src[2], v3 = src[3];
            const float v4 = src[4], v5 = src[5], v6 = src[6], v7 = src[7];
            rs += ((v0 + v1) + (v2 + v3)) + ((v4 + v5) + (v6 + v7));
            short8 f;
            f[0] = f2bf(v0); f[1] = f2bf(v1); f[2] = f2bf(v2); f[3] = f2bf(v3);
            f[4] = f2bf(v4); f[5] = f2bf(v5); f[6] = f2bf(v6); f[7] = f2bf(v7);
            acc = __builtin_amdgcn_mfma_f32_16x16x32_bf16(f, f, acc, 0, 0, 0);
        }
        __syncthreads();   // tile fully consumed before next stage overwrites
    }

    // Row sum: combine the 4 k-slice lanes of each row (bits 4,5 of lane).
    rs += __shfl_xor(rs, 16);
    rs += __shfl_xor(rs, 32);

    // Block reduction: 4 waves' C tiles + row sums via LDS (epilogue only).
    __shared__ float cpart[4][D][D];
    __shared__ float spart[4][D];
    // C/D layout: col = lane&15, row = (lane>>4)*4 + i   [m89-verified]
#pragma unroll
    for (int i = 0; i < 4; ++i)
        cpart[wid][kg * 4 + i][row] = acc[i];
    if (lane < D) spart[wid][lane] = rs;
    __syncthreads();

    const int d = tid >> 4, e = tid & 15;
    if (d <= e) {
        const float s = (cpart[0][d][e] + cpart[1][d][e]) +
                        (cpart[2][d][e] + cpart[3][d][e]);
        part[tri_idx(d, e) * G + blockIdx.x] = s;
    }
    if (tid < D) {
        const float s = (spart[0][tid] + spart[1][tid]) +
                        (spart[2][tid] + spart[3][tid]);
        part[(NPAIR + tid) * G + blockIdx.x] = s;
    }
}

// Pass 2 (single block, 256 threads): reduce partials, build cov, invert
// 16x16 via cooperative Gauss-Jordan, emit (1/N) * sum(P .* S).
__global__ void finalize_kernel(const float* __restrict__ part,
                                float* __restrict__ out) {
    __shared__ float Stri[NPAIR];
    __shared__ float Ssum[D];
    __shared__ float A[D][2 * D + 1];   // [cov | I], padded row

    const int tid  = threadIdx.x;
    const int lane = tid & 63;
    const int wv   = tid >> 6;

    // 1) Reduce G block-partials per value: one wave per value row.
    for (int vi = wv; vi < NVALS; vi += 4) {
        float s = 0.0f;
#pragma unroll
        for (int j = 0; j < GJ; ++j)
            s += part[vi * G + j * 64 + lane];
        s = wave_reduce(s);
        if (lane == 0) {
            if (vi < NPAIR) Stri[vi]         = s;
            else            Ssum[vi - NPAIR] = s;
        }
    }
    __syncthreads();

    // 2) Augmented matrix [cov | I]
    {
        const int d = tid >> 4, e = tid & 15;
        const int lo = d < e ? d : e, hi = d < e ? e : d;
        const float invN = 1.0f / (float)NTOT;
        const float cov = (Stri[tri_idx(lo, hi)] -
                           Ssum[d] * Ssum[e] * invN) /
                          (float)(NTOT - 1);
        A[d][e]     = cov;
        A[d][D + e] = (d == e) ? 1.0f : 0.0f;
    }
    __syncthreads();

    // 3) Gauss-Jordan (no pivoting; cov ~ 0.01*I, well-conditioned).
    const int r0 = tid >> 5;   // 0..7
    const int c0 = tid & 31;   // 0..31
    const int r1 = r0 + 8;
    for (int k = 0; k < D; ++k) {
        const float pivinv = 1.0f / A[k][k];
        __syncthreads();
        if (tid < 32) A[k][tid] *= pivinv;
        __syncthreads();
        const float f0 = A[r0][k];
        const float f1 = A[r1][k];
        __syncthreads();
        const float akc = A[k][c0];
        if (r0 != k) A[r0][c0] -= f0 * akc;
        if (r1 != k) A[r1][c0] -= f1 * akc;
        __syncthreads();
    }

    // 4) result = (1/N) * sum_{d,e} P[d][e] * S[d][e]
    float term;
    {
        const int d = tid >> 4, e = tid & 15;
        const int lo = d < e ? d : e, hi = d < e ? e : d;
        float p = A[d][D + e];
        const float scale = 1.0f;  // OFF_DIAGONAL_SCALE
        if (d != e) p *= scale;
        term = p * Stri[tri_idx(lo, hi)];
    }
    term = wave_reduce(term);

    __shared__ float wsum[4];
    if (lane == 0) wsum[wv] = term;
    __syncthreads();
    if (tid == 0) {
        const float tot = (wsum[0] + wsum[1]) + (wsum[2] + wsum[3]);
        out[0] = tot / (float)NTOT;
    }
}

extern "C" void kernel_launch(void* const* d_in, const int* in_sizes, int n_in,
                              void* d_out, int out_size, void* d_ws, size_t ws_size,
                              hipStream_t stream) {
    const float* y_true = (const float*)d_in[0];
    const float* y_pred = (const float*)d_in[1];
    float* out  = (float*)d_out;
    float* part = (float*)d_ws;   // needs NVALS * G * 4 = 1,050,624 bytes

    hipLaunchKernelGGL(gram_mfma, dim3(G), dim3(256), 0, stream,
                       y_true, y_pred, part);
    hipLaunchKernelGGL(finalize_kernel, dim3(1), dim3(256), 0, stream,
                       part, out);
}